// Round 1
// baseline (1101.723 us; speedup 1.0000x reference)
//
#include <hip/hip_runtime.h>

#define NN 50000
#define NE 800000
#define NG 512
#define INDIM 100
#define OUTD 24

// ---------------- scatter-add aggregation ----------------
// agg[dst] += feat[src], one thread per (edge, dim)

__global__ __launch_bounds__(256) void k_scatter100(const float* __restrict__ x,
                                                    const int* __restrict__ ei,
                                                    float* __restrict__ agg) {
    unsigned tid = blockIdx.x * 256u + threadIdx.x;
    unsigned e = tid >> 7, d = tid & 127u;
    if (e >= NE || d >= INDIM) return;
    int s = ei[e];
    int t = ei[NE + e];
    atomicAdd(&agg[t * INDIM + d], x[s * INDIM + d]);
}

__global__ __launch_bounds__(256) void k_scatter64(const float* __restrict__ h,
                                                   const int* __restrict__ ei,
                                                   float* __restrict__ agg) {
    unsigned tid = blockIdx.x * 256u + threadIdx.x;
    unsigned e = tid >> 6, d = tid & 63u;
    if (e >= NE) return;
    int s = ei[e];
    int t = ei[NE + e];
    atomicAdd(&agg[t * 64 + d], h[s * 64 + d]);
}

// ---------------- GIN layer MLPs (per-node, one wave/block) ----------------

__global__ __launch_bounds__(64) void k_mlp0(const float* __restrict__ x,
                                             const float* __restrict__ agg,
                                             const float* __restrict__ w1,
                                             const float* __restrict__ b1,
                                             const float* __restrict__ w2,
                                             const float* __restrict__ b2,
                                             float* __restrict__ out) {
    __shared__ float zs[INDIM];
    __shared__ float ts[64];
    int node = blockIdx.x;
    int lane = threadIdx.x;
    const float* xr = x + node * INDIM;
    const float* ar = agg + node * INDIM;
    zs[lane] = xr[lane] + ar[lane];
    if (lane < INDIM - 64) zs[64 + lane] = xr[64 + lane] + ar[64 + lane];
    __syncthreads();
    float acc = b1[lane];
#pragma unroll 4
    for (int k = 0; k < INDIM; ++k) acc = fmaf(zs[k], w1[k * 64 + lane], acc);
    ts[lane] = fmaxf(acc, 0.f);
    __syncthreads();
    float acc2 = b2[lane];
#pragma unroll 4
    for (int k = 0; k < 64; ++k) acc2 = fmaf(ts[k], w2[k * 64 + lane], acc2);
    out[node * 64 + lane] = fmaxf(acc2, 0.f);  // inter-layer ReLU fused
}

__global__ __launch_bounds__(64) void k_mlp64(const float* __restrict__ hprev,
                                              const float* __restrict__ agg,
                                              const float* __restrict__ w1,
                                              const float* __restrict__ b1,
                                              const float* __restrict__ w2,
                                              const float* __restrict__ b2,
                                              float* __restrict__ out) {
    __shared__ float zs[64];
    __shared__ float ts[64];
    int node = blockIdx.x;
    int lane = threadIdx.x;
    zs[lane] = hprev[node * 64 + lane] + agg[node * 64 + lane];
    __syncthreads();
    float acc = b1[lane];
#pragma unroll 4
    for (int k = 0; k < 64; ++k) acc = fmaf(zs[k], w1[k * 64 + lane], acc);
    ts[lane] = fmaxf(acc, 0.f);
    __syncthreads();
    float acc2 = b2[lane];
#pragma unroll 4
    for (int k = 0; k < 64; ++k) acc2 = fmaf(ts[k], w2[k * 64 + lane], acc2);
    out[node * 64 + lane] = fmaxf(acc2, 0.f);
}

// ---------------- JK concat -> linear -> global_add_pool ----------------

__global__ __launch_bounds__(64) void k_jk(const float* __restrict__ h1,
                                           const float* __restrict__ h2,
                                           const float* __restrict__ h3,
                                           const float* __restrict__ jkw,
                                           const float* __restrict__ jkb,
                                           const int* __restrict__ batch,
                                           float* __restrict__ g) {
    __shared__ float zs[192];
    int node = blockIdx.x;
    int lane = threadIdx.x;
    zs[lane]       = h1[node * 64 + lane];
    zs[64 + lane]  = h2[node * 64 + lane];
    zs[128 + lane] = h3[node * 64 + lane];
    __syncthreads();
    float acc = jkb[lane];
#pragma unroll 4
    for (int k = 0; k < 192; ++k) acc = fmaf(zs[k], jkw[k * 64 + lane], acc);
    atomicAdd(&g[batch[node] * 64 + lane], acc);
}

// ---------------- final head: ffn (lin->bn->relu->lin) -> out linear ----------------

__global__ __launch_bounds__(64) void k_final(const float* __restrict__ g,
                                              const float* __restrict__ w1,
                                              const float* __restrict__ b1,
                                              const float* __restrict__ bng,
                                              const float* __restrict__ bnb,
                                              const float* __restrict__ bnm,
                                              const float* __restrict__ bnv,
                                              const float* __restrict__ w2,
                                              const float* __restrict__ b2,
                                              const float* __restrict__ ow,
                                              const float* __restrict__ ob,
                                              float* __restrict__ out) {
    __shared__ float gs[64];
    __shared__ float t2[64];
    __shared__ float t3[64];
    int gr = blockIdx.x;
    int lane = threadIdx.x;
    gs[lane] = g[gr * 64 + lane];
    __syncthreads();
    float acc = b1[lane];
#pragma unroll 4
    for (int k = 0; k < 64; ++k) acc = fmaf(gs[k], w1[k * 64 + lane], acc);
    // batchnorm (eval)
    acc = (acc - bnm[lane]) * rsqrtf(bnv[lane] + 1e-5f) * bng[lane] + bnb[lane];
    t2[lane] = fmaxf(acc, 0.f);
    __syncthreads();
    float acc2 = b2[lane];
#pragma unroll 4
    for (int k = 0; k < 64; ++k) acc2 = fmaf(t2[k], w2[k * 64 + lane], acc2);
    t3[lane] = acc2;  // NO relu after ffn second linear
    __syncthreads();
    if (lane < OUTD) {
        float acc3 = ob[lane];
#pragma unroll 4
        for (int k = 0; k < 64; ++k) acc3 = fmaf(t3[k], ow[k * OUTD + lane], acc3);
        out[gr * OUTD + lane] = acc3;
    }
}

extern "C" void kernel_launch(void* const* d_in, const int* in_sizes, int n_in,
                              void* d_out, int out_size, void* d_ws, size_t ws_size,
                              hipStream_t stream) {
    const float* x     = (const float*)d_in[0];
    const int*   ei    = (const int*)d_in[1];
    const int*   batch = (const int*)d_in[2];
    const float* w1_0 = (const float*)d_in[3];
    const float* b1_0 = (const float*)d_in[4];
    const float* w2_0 = (const float*)d_in[5];
    const float* b2_0 = (const float*)d_in[6];
    const float* w1_1 = (const float*)d_in[7];
    const float* b1_1 = (const float*)d_in[8];
    const float* w2_1 = (const float*)d_in[9];
    const float* b2_1 = (const float*)d_in[10];
    const float* w1_2 = (const float*)d_in[11];
    const float* b1_2 = (const float*)d_in[12];
    const float* w2_2 = (const float*)d_in[13];
    const float* b2_2 = (const float*)d_in[14];
    const float* jk_w = (const float*)d_in[15];
    const float* jk_b = (const float*)d_in[16];
    const float* ffn_w1 = (const float*)d_in[17];
    const float* ffn_b1 = (const float*)d_in[18];
    const float* bn_g = (const float*)d_in[19];
    const float* bn_b = (const float*)d_in[20];
    const float* bn_m = (const float*)d_in[21];
    const float* bn_v = (const float*)d_in[22];
    const float* ffn_w2 = (const float*)d_in[23];
    const float* ffn_b2 = (const float*)d_in[24];
    const float* out_w  = (const float*)d_in[25];
    const float* out_b  = (const float*)d_in[26];

    float* ws   = (float*)d_ws;
    float* agg  = ws;                 // 5,000,000 floats (100-dim layer0; reused 64-dim later)
    float* h1   = ws + 5000000;       // 3,200,000
    float* h2   = h1 + 3200000;       // 3,200,000
    float* h3   = h2 + 3200000;       // 3,200,000
    float* g    = h3 + 3200000;       // 32,768
    // total ~58.5 MB

    // ---- layer 0 (IN_DIM=100) ----
    hipMemsetAsync(agg, 0, (size_t)NN * INDIM * sizeof(float), stream);
    k_scatter100<<<(NE * 128) / 256, 256, 0, stream>>>(x, ei, agg);
    k_mlp0<<<NN, 64, 0, stream>>>(x, agg, w1_0, b1_0, w2_0, b2_0, h1);

    // ---- layer 1 ----
    hipMemsetAsync(agg, 0, (size_t)NN * 64 * sizeof(float), stream);
    k_scatter64<<<(NE * 64) / 256, 256, 0, stream>>>(h1, ei, agg);
    k_mlp64<<<NN, 64, 0, stream>>>(h1, agg, w1_1, b1_1, w2_1, b2_1, h2);

    // ---- layer 2 ----
    hipMemsetAsync(agg, 0, (size_t)NN * 64 * sizeof(float), stream);
    k_scatter64<<<(NE * 64) / 256, 256, 0, stream>>>(h2, ei, agg);
    k_mlp64<<<NN, 64, 0, stream>>>(h2, agg, w1_2, b1_2, w2_2, b2_2, h3);

    // ---- JK + pool ----
    hipMemsetAsync(g, 0, (size_t)NG * 64 * sizeof(float), stream);
    k_jk<<<NN, 64, 0, stream>>>(h1, h2, h3, jk_w, jk_b, batch, g);

    // ---- head ----
    k_final<<<NG, 64, 0, stream>>>(g, ffn_w1, ffn_b1, bn_g, bn_b, bn_m, bn_v,
                                   ffn_w2, ffn_b2, out_w, out_b, (float*)d_out);
}

// Round 2
// 653.229 us; speedup vs baseline: 1.6866x; 1.6866x over previous
//
#include <hip/hip_runtime.h>

#define NN 50000
#define NE 800000
#define NG 512
#define INDIM 100
#define OUTD 24
#define SCAN_T 1024
#define CHUNK 49  // ceil(50000/1024)

// ---------------- CSR build ----------------

__global__ __launch_bounds__(256) void k_hist(const int* __restrict__ ei, int* __restrict__ deg) {
    unsigned e = blockIdx.x * 256u + threadIdx.x;
    if (e >= NE) return;
    atomicAdd(&deg[ei[NE + e]], 1);
}

__global__ __launch_bounds__(SCAN_T) void k_scan(const int* __restrict__ deg,
                                                 int* __restrict__ rowptr,
                                                 int* __restrict__ cursor) {
    __shared__ int ssum[SCAN_T];
    int t = threadIdx.x;
    int start = t * CHUNK;
    int end = min(start + CHUNK, NN);
    int local = 0;
    for (int i = start; i < end; ++i) local += deg[i];
    ssum[t] = local;
    __syncthreads();
    // Hillis-Steele inclusive scan
    for (int off = 1; off < SCAN_T; off <<= 1) {
        int v = (t >= off) ? ssum[t - off] : 0;
        __syncthreads();
        ssum[t] += v;
        __syncthreads();
    }
    int run = ssum[t] - local;  // exclusive prefix
    for (int i = start; i < end; ++i) {
        rowptr[i] = run;
        cursor[i] = run;
        run += deg[i];
    }
    if (t == SCAN_T - 1) rowptr[NN] = run;
}

__global__ __launch_bounds__(256) void k_fill(const int* __restrict__ ei,
                                              int* __restrict__ cursor,
                                              int* __restrict__ csr) {
    unsigned e = blockIdx.x * 256u + threadIdx.x;
    if (e >= NE) return;
    int s = ei[e];
    int d = ei[NE + e];
    int pos = atomicAdd(&cursor[d], 1);
    csr[pos] = s;
}

// ---------------- y0 = x @ w1_0 (no bias) ----------------

__global__ __launch_bounds__(64) void k_pre0(const float* __restrict__ x,
                                             const float* __restrict__ w1,
                                             float* __restrict__ y) {
    __shared__ float xs[INDIM];
    int n = blockIdx.x, lane = threadIdx.x;
    const float* xr = x + (size_t)n * INDIM;
    xs[lane] = xr[lane];
    if (lane < INDIM - 64) xs[64 + lane] = xr[64 + lane];
    __syncthreads();
    float a = 0.f;
#pragma unroll 4
    for (int k = 0; k < INDIM; ++k) a = fmaf(xs[k], w1[k * 64 + lane], a);
    y[(size_t)n * 64 + lane] = a;
}

// ---------------- fused layer: gather-agg(y) -> MLP -> jk partial (+ y_next) ----------------
// y holds h_prev @ w1 for this layer; aggregation is exact by linearity.

template <bool HAS_NEXT, bool ADD_JK>
__global__ __launch_bounds__(64) void k_layer(const float* __restrict__ y,
                                              const int* __restrict__ rowptr,
                                              const int* __restrict__ csr,
                                              const float* __restrict__ b1,
                                              const float* __restrict__ w2,
                                              const float* __restrict__ b2,
                                              const float* __restrict__ wnext,
                                              const float* __restrict__ jkw,  // pre-offset for layer
                                              float* __restrict__ ynext,
                                              float* __restrict__ jkacc) {
    int n = blockIdx.x, lane = threadIdx.x;
    int beg = rowptr[n], end = rowptr[n + 1];
    float acc = y[(size_t)n * 64 + lane];
    for (int e = beg; e < end; ++e) {
        acc += y[(size_t)csr[e] * 64 + lane];
    }
    float t = fmaxf(acc + b1[lane], 0.f);
    __shared__ float ts[64];
    __shared__ float hs[64];
    ts[lane] = t;
    __syncthreads();
    float h = b2[lane];
#pragma unroll 8
    for (int k = 0; k < 64; ++k) h = fmaf(ts[k], w2[k * 64 + lane], h);
    h = fmaxf(h, 0.f);  // inter-layer ReLU (jk='cat' applies on every layer)
    hs[lane] = h;
    __syncthreads();
    float jk = ADD_JK ? jkacc[(size_t)n * 64 + lane] : 0.f;
    float yn = 0.f;
#pragma unroll 8
    for (int k = 0; k < 64; ++k) {
        float hk = hs[k];
        jk = fmaf(hk, jkw[k * 64 + lane], jk);
        if (HAS_NEXT) yn = fmaf(hk, wnext[k * 64 + lane], yn);
    }
    jkacc[(size_t)n * 64 + lane] = jk;
    if (HAS_NEXT) ynext[(size_t)n * 64 + lane] = yn;
}

// ---------------- pool: g[batch[n]] += jkacc[n] + jk_b ----------------

__global__ __launch_bounds__(256) void k_pool(const float* __restrict__ jkacc,
                                              const float* __restrict__ jkb,
                                              const int* __restrict__ batch,
                                              float* __restrict__ g) {
    unsigned tid = blockIdx.x * 256u + threadIdx.x;
    if (tid >= NN * 64u) return;
    unsigned n = tid >> 6, lane = tid & 63u;
    atomicAdd(&g[batch[n] * 64 + lane], jkacc[tid] + jkb[lane]);
}

// ---------------- final head ----------------

__global__ __launch_bounds__(64) void k_final(const float* __restrict__ g,
                                              const float* __restrict__ w1,
                                              const float* __restrict__ b1,
                                              const float* __restrict__ bng,
                                              const float* __restrict__ bnb,
                                              const float* __restrict__ bnm,
                                              const float* __restrict__ bnv,
                                              const float* __restrict__ w2,
                                              const float* __restrict__ b2,
                                              const float* __restrict__ ow,
                                              const float* __restrict__ ob,
                                              float* __restrict__ out) {
    __shared__ float gs[64];
    __shared__ float t2[64];
    __shared__ float t3[64];
    int gr = blockIdx.x, lane = threadIdx.x;
    gs[lane] = g[gr * 64 + lane];
    __syncthreads();
    float acc = b1[lane];
#pragma unroll 8
    for (int k = 0; k < 64; ++k) acc = fmaf(gs[k], w1[k * 64 + lane], acc);
    acc = (acc - bnm[lane]) * rsqrtf(bnv[lane] + 1e-5f) * bng[lane] + bnb[lane];
    t2[lane] = fmaxf(acc, 0.f);
    __syncthreads();
    float acc2 = b2[lane];
#pragma unroll 8
    for (int k = 0; k < 64; ++k) acc2 = fmaf(t2[k], w2[k * 64 + lane], acc2);
    t3[lane] = acc2;
    __syncthreads();
    if (lane < OUTD) {
        float acc3 = ob[lane];
#pragma unroll 8
        for (int k = 0; k < 64; ++k) acc3 = fmaf(t3[k], ow[k * OUTD + lane], acc3);
        out[gr * OUTD + lane] = acc3;
    }
}

extern "C" void kernel_launch(void* const* d_in, const int* in_sizes, int n_in,
                              void* d_out, int out_size, void* d_ws, size_t ws_size,
                              hipStream_t stream) {
    const float* x     = (const float*)d_in[0];
    const int*   ei    = (const int*)d_in[1];
    const int*   batch = (const int*)d_in[2];
    const float* w1_0 = (const float*)d_in[3];
    const float* b1_0 = (const float*)d_in[4];
    const float* w2_0 = (const float*)d_in[5];
    const float* b2_0 = (const float*)d_in[6];
    const float* w1_1 = (const float*)d_in[7];
    const float* b1_1 = (const float*)d_in[8];
    const float* w2_1 = (const float*)d_in[9];
    const float* b2_1 = (const float*)d_in[10];
    const float* w1_2 = (const float*)d_in[11];
    const float* b1_2 = (const float*)d_in[12];
    const float* w2_2 = (const float*)d_in[13];
    const float* b2_2 = (const float*)d_in[14];
    const float* jk_w = (const float*)d_in[15];
    const float* jk_b = (const float*)d_in[16];
    const float* ffn_w1 = (const float*)d_in[17];
    const float* ffn_b1 = (const float*)d_in[18];
    const float* bn_g = (const float*)d_in[19];
    const float* bn_b = (const float*)d_in[20];
    const float* bn_m = (const float*)d_in[21];
    const float* bn_v = (const float*)d_in[22];
    const float* ffn_w2 = (const float*)d_in[23];
    const float* ffn_b2 = (const float*)d_in[24];
    const float* out_w  = (const float*)d_in[25];
    const float* out_b  = (const float*)d_in[26];

    // workspace layout
    float* ws = (float*)d_ws;
    float* ya    = ws;                      // 3.2M floats
    float* yb    = ya + 3200000;            // 3.2M
    float* jkacc = yb + 3200000;            // 3.2M
    float* g     = jkacc + 3200000;         // 32768
    int*   deg    = (int*)(g + 32768);      // 50000
    int*   rowptr = deg + NN;               // 50001
    int*   cursor = rowptr + NN + 1;        // 50000
    int*   csr    = cursor + NN;            // 800000
    // total ~42.4 MB

    // ---- CSR build ----
    hipMemsetAsync(deg, 0, NN * sizeof(int), stream);
    hipMemsetAsync(g, 0, NG * 64 * sizeof(float), stream);
    k_hist<<<(NE + 255) / 256, 256, 0, stream>>>(ei, deg);
    k_scan<<<1, SCAN_T, 0, stream>>>(deg, rowptr, cursor);
    k_fill<<<(NE + 255) / 256, 256, 0, stream>>>(ei, cursor, csr);

    // ---- y0 = x @ w1_0 ----
    k_pre0<<<NN, 64, 0, stream>>>(x, w1_0, ya);

    // ---- layer 0: ya -> (jkacc=, yb = h1 @ w1_1) ----
    k_layer<true, false><<<NN, 64, 0, stream>>>(ya, rowptr, csr, b1_0, w2_0, b2_0,
                                                w1_1, jk_w, yb, jkacc);
    // ---- layer 1: yb -> (jkacc+=, ya = h2 @ w1_2) ----
    k_layer<true, true><<<NN, 64, 0, stream>>>(yb, rowptr, csr, b1_1, w2_1, b2_1,
                                               w1_2, jk_w + 64 * 64, ya, jkacc);
    // ---- layer 2: ya -> (jkacc+=) ----
    k_layer<false, true><<<NN, 64, 0, stream>>>(ya, rowptr, csr, b1_2, w2_2, b2_2,
                                                nullptr, jk_w + 2 * 64 * 64, nullptr, jkacc);

    // ---- pool ----
    k_pool<<<(NN * 64 + 255) / 256, 256, 0, stream>>>(jkacc, jk_b, batch, g);

    // ---- head ----
    k_final<<<NG, 64, 0, stream>>>(g, ffn_w1, ffn_b1, bn_g, bn_b, bn_m, bn_v,
                                   ffn_w2, ffn_b2, out_w, out_b, (float*)d_out);
}

// Round 3
// 649.802 us; speedup vs baseline: 1.6955x; 1.0053x over previous
//
#include <hip/hip_runtime.h>

#define NN 50000
#define NE 800000
#define NG 512
#define INDIM 100
#define OUTD 24
#define NB_SCAN 196  // ceil(50000/256)

// ---------------- CSR build ----------------

__global__ __launch_bounds__(256) void k_hist(const int* __restrict__ ei, int* __restrict__ deg) {
    unsigned e = blockIdx.x * 256u + threadIdx.x;
    if (e >= NE) return;
    atomicAdd(&deg[ei[NE + e]], 1);
}

// pass 1: per-block exclusive scan of deg -> rowptr (block-local), block sums out
__global__ __launch_bounds__(256) void k_scan1(const int* __restrict__ deg,
                                               int* __restrict__ rowptr,
                                               int* __restrict__ bsums) {
    __shared__ int s[256];
    int t = threadIdx.x;
    int i = blockIdx.x * 256 + t;
    int v = (i < NN) ? deg[i] : 0;
    s[t] = v;
    __syncthreads();
    for (int off = 1; off < 256; off <<= 1) {
        int u = (t >= off) ? s[t - off] : 0;
        __syncthreads();
        s[t] += u;
        __syncthreads();
    }
    if (i < NN) rowptr[i] = s[t] - v;  // exclusive, block-local
    if (t == 255) bsums[blockIdx.x] = s[255];
}

// pass 2: scan the 196 block sums (one block)
__global__ __launch_bounds__(256) void k_scan2(const int* __restrict__ bsums,
                                               int* __restrict__ boffs) {
    __shared__ int s[256];
    int t = threadIdx.x;
    int v = (t < NB_SCAN) ? bsums[t] : 0;
    s[t] = v;
    __syncthreads();
    for (int off = 1; off < 256; off <<= 1) {
        int u = (t >= off) ? s[t - off] : 0;
        __syncthreads();
        s[t] += u;
        __syncthreads();
    }
    if (t < NB_SCAN) boffs[t] = s[t] - v;  // exclusive
}

// pass 3: add block offsets, init cursor, set rowptr[NN]
__global__ __launch_bounds__(256) void k_scan3(int* __restrict__ rowptr,
                                               int* __restrict__ cursor,
                                               const int* __restrict__ boffs) {
    int i = blockIdx.x * 256 + threadIdx.x;
    if (i >= NN) return;
    int v = rowptr[i] + boffs[blockIdx.x];
    rowptr[i] = v;
    cursor[i] = v;
    if (i == 0) rowptr[NN] = NE;  // total is statically known
}

__global__ __launch_bounds__(256) void k_fill(const int* __restrict__ ei,
                                              int* __restrict__ cursor,
                                              int* __restrict__ csr) {
    unsigned e = blockIdx.x * 256u + threadIdx.x;
    if (e >= NE) return;
    int s = ei[e];
    int d = ei[NE + e];
    int pos = atomicAdd(&cursor[d], 1);
    csr[pos] = s;
}

// ---------------- y0 = x @ w1_0 (no bias): 4 nodes/block, one wave each ----------------

__global__ __launch_bounds__(256) void k_pre0(const float* __restrict__ x,
                                              const float* __restrict__ w1,
                                              float* __restrict__ y) {
    __shared__ float xs[4][INDIM];
    int sub = threadIdx.x >> 6, lane = threadIdx.x & 63;
    int n = blockIdx.x * 4 + sub;
    const float* xr = x + (size_t)n * INDIM;
    xs[sub][lane] = xr[lane];
    if (lane < INDIM - 64) xs[sub][64 + lane] = xr[64 + lane];
    __syncthreads();
    float a = 0.f;
#pragma unroll 4
    for (int k = 0; k < INDIM; ++k) a = fmaf(xs[sub][k], w1[k * 64 + lane], a);
    y[(size_t)n * 64 + lane] = a;
}

// ---------------- fused layer: gather-agg(y) -> MLP -> jk partial (+ y_next) ----------------
// y holds h_prev @ w1 for this layer (exact by linearity). 4 nodes/block.
// LAST layer (HAS_NEXT=false) atomically pools jk result into g instead of writing jkacc.

template <bool HAS_NEXT, bool ADD_JK>
__global__ __launch_bounds__(256) void k_layer(const float* __restrict__ y,
                                               const int* __restrict__ rowptr,
                                               const int* __restrict__ csr,
                                               const float* __restrict__ b1,
                                               const float* __restrict__ w2,
                                               const float* __restrict__ b2,
                                               const float* __restrict__ wnext,
                                               const float* __restrict__ jkw,  // pre-offset for layer
                                               float* __restrict__ ynext,
                                               float* __restrict__ jkacc,
                                               const float* __restrict__ jkb,
                                               const int* __restrict__ batch,
                                               float* __restrict__ g) {
    __shared__ float ts[4][64];
    __shared__ float hs[4][64];
    int sub = threadIdx.x >> 6, lane = threadIdx.x & 63;
    int n = blockIdx.x * 4 + sub;
    int beg = rowptr[n], end = rowptr[n + 1];
    float acc = y[(size_t)n * 64 + lane];
    for (int e = beg; e < end; ++e) {
        acc += y[(size_t)csr[e] * 64 + lane];
    }
    ts[sub][lane] = fmaxf(acc + b1[lane], 0.f);
    __syncthreads();
    float h = b2[lane];
#pragma unroll 8
    for (int k = 0; k < 64; ++k) h = fmaf(ts[sub][k], w2[k * 64 + lane], h);
    h = fmaxf(h, 0.f);  // inter-layer ReLU (jk='cat' applies it on every layer)
    hs[sub][lane] = h;
    __syncthreads();
    float jk = ADD_JK ? jkacc[(size_t)n * 64 + lane] : 0.f;
    float yn = 0.f;
#pragma unroll 8
    for (int k = 0; k < 64; ++k) {
        float hk = hs[sub][k];
        jk = fmaf(hk, jkw[k * 64 + lane], jk);
        if (HAS_NEXT) yn = fmaf(hk, wnext[k * 64 + lane], yn);
    }
    if (HAS_NEXT) {
        jkacc[(size_t)n * 64 + lane] = jk;
        ynext[(size_t)n * 64 + lane] = yn;
    } else {
        // final layer: fused global_add_pool of (jk + jk_b)
        atomicAdd(&g[batch[n] * 64 + lane], jk + jkb[lane]);
    }
}

// ---------------- final head ----------------

__global__ __launch_bounds__(64) void k_final(const float* __restrict__ g,
                                              const float* __restrict__ w1,
                                              const float* __restrict__ b1,
                                              const float* __restrict__ bng,
                                              const float* __restrict__ bnb,
                                              const float* __restrict__ bnm,
                                              const float* __restrict__ bnv,
                                              const float* __restrict__ w2,
                                              const float* __restrict__ b2,
                                              const float* __restrict__ ow,
                                              const float* __restrict__ ob,
                                              float* __restrict__ out) {
    __shared__ float gs[64];
    __shared__ float t2[64];
    __shared__ float t3[64];
    int gr = blockIdx.x, lane = threadIdx.x;
    gs[lane] = g[gr * 64 + lane];
    __syncthreads();
    float acc = b1[lane];
#pragma unroll 8
    for (int k = 0; k < 64; ++k) acc = fmaf(gs[k], w1[k * 64 + lane], acc);
    acc = (acc - bnm[lane]) * rsqrtf(bnv[lane] + 1e-5f) * bng[lane] + bnb[lane];
    t2[lane] = fmaxf(acc, 0.f);
    __syncthreads();
    float acc2 = b2[lane];
#pragma unroll 8
    for (int k = 0; k < 64; ++k) acc2 = fmaf(t2[k], w2[k * 64 + lane], acc2);
    t3[lane] = acc2;
    __syncthreads();
    if (lane < OUTD) {
        float acc3 = ob[lane];
#pragma unroll 8
        for (int k = 0; k < 64; ++k) acc3 = fmaf(t3[k], ow[k * OUTD + lane], acc3);
        out[gr * OUTD + lane] = acc3;
    }
}

extern "C" void kernel_launch(void* const* d_in, const int* in_sizes, int n_in,
                              void* d_out, int out_size, void* d_ws, size_t ws_size,
                              hipStream_t stream) {
    const float* x     = (const float*)d_in[0];
    const int*   ei    = (const int*)d_in[1];
    const int*   batch = (const int*)d_in[2];
    const float* w1_0 = (const float*)d_in[3];
    const float* b1_0 = (const float*)d_in[4];
    const float* w2_0 = (const float*)d_in[5];
    const float* b2_0 = (const float*)d_in[6];
    const float* w1_1 = (const float*)d_in[7];
    const float* b1_1 = (const float*)d_in[8];
    const float* w2_1 = (const float*)d_in[9];
    const float* b2_1 = (const float*)d_in[10];
    const float* w1_2 = (const float*)d_in[11];
    const float* b1_2 = (const float*)d_in[12];
    const float* w2_2 = (const float*)d_in[13];
    const float* b2_2 = (const float*)d_in[14];
    const float* jk_w = (const float*)d_in[15];
    const float* jk_b = (const float*)d_in[16];
    const float* ffn_w1 = (const float*)d_in[17];
    const float* ffn_b1 = (const float*)d_in[18];
    const float* bn_g = (const float*)d_in[19];
    const float* bn_b = (const float*)d_in[20];
    const float* bn_m = (const float*)d_in[21];
    const float* bn_v = (const float*)d_in[22];
    const float* ffn_w2 = (const float*)d_in[23];
    const float* ffn_b2 = (const float*)d_in[24];
    const float* out_w  = (const float*)d_in[25];
    const float* out_b  = (const float*)d_in[26];

    // workspace layout
    float* ws = (float*)d_ws;
    float* ya    = ws;                      // 3.2M floats
    float* yb    = ya + 3200000;            // 3.2M
    float* jkacc = yb + 3200000;            // 3.2M
    float* g     = jkacc + 3200000;         // 32768
    int*   deg    = (int*)(g + 32768);      // 50000
    int*   rowptr = deg + NN;               // 50001
    int*   cursor = rowptr + NN + 1;        // 50000
    int*   csr    = cursor + NN;            // 800000
    int*   bsums  = csr + NE;               // 196
    int*   boffs  = bsums + NB_SCAN;        // 196

    // ---- CSR build ----
    hipMemsetAsync(deg, 0, NN * sizeof(int), stream);
    hipMemsetAsync(g, 0, NG * 64 * sizeof(float), stream);
    k_hist<<<(NE + 255) / 256, 256, 0, stream>>>(ei, deg);
    k_scan1<<<NB_SCAN, 256, 0, stream>>>(deg, rowptr, bsums);
    k_scan2<<<1, 256, 0, stream>>>(bsums, boffs);
    k_scan3<<<NB_SCAN, 256, 0, stream>>>(rowptr, cursor, boffs);
    k_fill<<<(NE + 255) / 256, 256, 0, stream>>>(ei, cursor, csr);

    // ---- y0 = x @ w1_0 ----
    k_pre0<<<NN / 4, 256, 0, stream>>>(x, w1_0, ya);

    // ---- layer 0: ya -> (jkacc=, yb = h1 @ w1_1) ----
    k_layer<true, false><<<NN / 4, 256, 0, stream>>>(ya, rowptr, csr, b1_0, w2_0, b2_0,
                                                     w1_1, jk_w, yb, jkacc,
                                                     nullptr, nullptr, nullptr);
    // ---- layer 1: yb -> (jkacc+=, ya = h2 @ w1_2) ----
    k_layer<true, true><<<NN / 4, 256, 0, stream>>>(yb, rowptr, csr, b1_1, w2_1, b2_1,
                                                    w1_2, jk_w + 64 * 64, ya, jkacc,
                                                    nullptr, nullptr, nullptr);
    // ---- layer 2: ya -> fused jk + pool into g ----
    k_layer<false, true><<<NN / 4, 256, 0, stream>>>(ya, rowptr, csr, b1_2, w2_2, b2_2,
                                                     nullptr, jk_w + 2 * 64 * 64, nullptr, jkacc,
                                                     jk_b, batch, g);

    // ---- head ----
    k_final<<<NG, 64, 0, stream>>>(g, ffn_w1, ffn_b1, bn_g, bn_b, bn_m, bn_v,
                                   ffn_w2, ffn_b2, out_w, out_b, (float*)d_out);
}

// Round 4
// 501.389 us; speedup vs baseline: 2.1973x; 1.2960x over previous
//
#include <hip/hip_runtime.h>

#define NN 50000
#define NE 800000
#define NG 512
#define INDIM 100
#define OUTD 24
#define NB_SCAN 196  // ceil(50000/256)

// ---------------- CSR build ----------------

__global__ __launch_bounds__(256) void k_hist(const int* __restrict__ ei, int* __restrict__ deg) {
    unsigned e = blockIdx.x * 256u + threadIdx.x;
    if (e >= NE) return;
    atomicAdd(&deg[ei[NE + e]], 1);
}

// pass 1: per-block exclusive scan of deg -> rowptr (block-local), block sums out
__global__ __launch_bounds__(256) void k_scan1(const int* __restrict__ deg,
                                               int* __restrict__ rowptr,
                                               int* __restrict__ bsums) {
    __shared__ int s[256];
    int t = threadIdx.x;
    int i = blockIdx.x * 256 + t;
    int v = (i < NN) ? deg[i] : 0;
    s[t] = v;
    __syncthreads();
    for (int off = 1; off < 256; off <<= 1) {
        int u = (t >= off) ? s[t - off] : 0;
        __syncthreads();
        s[t] += u;
        __syncthreads();
    }
    if (i < NN) rowptr[i] = s[t] - v;  // exclusive, block-local
    if (t == 255) bsums[blockIdx.x] = s[255];
}

// pass 2: scan the 196 block sums (one block)
__global__ __launch_bounds__(256) void k_scan2(const int* __restrict__ bsums,
                                               int* __restrict__ boffs) {
    __shared__ int s[256];
    int t = threadIdx.x;
    int v = (t < NB_SCAN) ? bsums[t] : 0;
    s[t] = v;
    __syncthreads();
    for (int off = 1; off < 256; off <<= 1) {
        int u = (t >= off) ? s[t - off] : 0;
        __syncthreads();
        s[t] += u;
        __syncthreads();
    }
    if (t < NB_SCAN) boffs[t] = s[t] - v;  // exclusive
}

// pass 3: add block offsets, init cursor, set rowptr[NN]
__global__ __launch_bounds__(256) void k_scan3(int* __restrict__ rowptr,
                                               int* __restrict__ cursor,
                                               const int* __restrict__ boffs) {
    int i = blockIdx.x * 256 + threadIdx.x;
    if (i >= NN) return;
    int v = rowptr[i] + boffs[blockIdx.x];
    rowptr[i] = v;
    cursor[i] = v;
    if (i == 0) rowptr[NN] = NE;  // total is statically known
}

__global__ __launch_bounds__(256) void k_fill(const int* __restrict__ ei,
                                              int* __restrict__ cursor,
                                              int* __restrict__ csr) {
    unsigned e = blockIdx.x * 256u + threadIdx.x;
    if (e >= NE) return;
    int s = ei[e];
    int d = ei[NE + e];
    int pos = atomicAdd(&cursor[d], 1);
    csr[pos] = s;
}

// ---------------- y0 = x @ w1_0 (no bias): 4 nodes/block, one wave each ----------------

__global__ __launch_bounds__(256) void k_pre0(const float* __restrict__ x,
                                              const float* __restrict__ w1,
                                              float* __restrict__ y) {
    __shared__ float xs[4][INDIM];
    int sub = threadIdx.x >> 6, lane = threadIdx.x & 63;
    int n = blockIdx.x * 4 + sub;
    const float* xr = x + (size_t)n * INDIM;
    xs[sub][lane] = xr[lane];
    if (lane < INDIM - 64) xs[sub][64 + lane] = xr[64 + lane];
    __syncthreads();
    float a = 0.f;
#pragma unroll 4
    for (int k = 0; k < INDIM; ++k) a = fmaf(xs[sub][k], w1[k * 64 + lane], a);
    y[(size_t)n * 64 + lane] = a;
}

// ---------------- fused layer: gather-agg(y) -> MLP -> jk partial (+ y_next) ----------------
// y holds h_prev @ w1 for this layer (exact by linearity). 4 nodes/block.
// Gather is 8-way unrolled with independent accumulators so 8 row-loads are
// in flight per wave (the round-3 kernel had 1 -> latency-bound at 140us).

template <bool HAS_NEXT, bool ADD_JK>
__global__ __launch_bounds__(256) void k_layer(const float* __restrict__ y,
                                               const int* __restrict__ rowptr,
                                               const int* __restrict__ csr,
                                               const float* __restrict__ b1,
                                               const float* __restrict__ w2,
                                               const float* __restrict__ b2,
                                               const float* __restrict__ wnext,
                                               const float* __restrict__ jkw,  // pre-offset for layer
                                               float* __restrict__ ynext,
                                               float* __restrict__ jkacc,
                                               const float* __restrict__ jkb,
                                               const int* __restrict__ batch,
                                               float* __restrict__ g) {
    __shared__ float ts[4][64];
    __shared__ float hs[4][64];
    int sub = threadIdx.x >> 6, lane = threadIdx.x & 63;
    // wave-uniform node index -> scalar rowptr/csr loads (K$) instead of VMEM
    int n = __builtin_amdgcn_readfirstlane(blockIdx.x * 4 + sub);
    int beg = rowptr[n], end = rowptr[n + 1];
    float a0 = y[(size_t)n * 64 + lane];
    float a1 = 0.f, a2 = 0.f, a3 = 0.f, a4 = 0.f, a5 = 0.f, a6 = 0.f, a7 = 0.f;
    int e = beg;
    for (; e + 8 <= end; e += 8) {
        int i0 = csr[e + 0], i1 = csr[e + 1], i2 = csr[e + 2], i3 = csr[e + 3];
        int i4 = csr[e + 4], i5 = csr[e + 5], i6 = csr[e + 6], i7 = csr[e + 7];
        a0 += y[(size_t)i0 * 64 + lane];
        a1 += y[(size_t)i1 * 64 + lane];
        a2 += y[(size_t)i2 * 64 + lane];
        a3 += y[(size_t)i3 * 64 + lane];
        a4 += y[(size_t)i4 * 64 + lane];
        a5 += y[(size_t)i5 * 64 + lane];
        a6 += y[(size_t)i6 * 64 + lane];
        a7 += y[(size_t)i7 * 64 + lane];
    }
    if (e + 4 <= end) {
        int i0 = csr[e + 0], i1 = csr[e + 1], i2 = csr[e + 2], i3 = csr[e + 3];
        a0 += y[(size_t)i0 * 64 + lane];
        a1 += y[(size_t)i1 * 64 + lane];
        a2 += y[(size_t)i2 * 64 + lane];
        a3 += y[(size_t)i3 * 64 + lane];
        e += 4;
    }
    if (e + 2 <= end) {
        int i0 = csr[e + 0], i1 = csr[e + 1];
        a0 += y[(size_t)i0 * 64 + lane];
        a1 += y[(size_t)i1 * 64 + lane];
        e += 2;
    }
    if (e < end) {
        a0 += y[(size_t)csr[e] * 64 + lane];
    }
    float acc = ((a0 + a1) + (a2 + a3)) + ((a4 + a5) + (a6 + a7));
    ts[sub][lane] = fmaxf(acc + b1[lane], 0.f);
    __syncthreads();
    float h = b2[lane];
#pragma unroll 8
    for (int k = 0; k < 64; ++k) h = fmaf(ts[sub][k], w2[k * 64 + lane], h);
    h = fmaxf(h, 0.f);  // inter-layer ReLU (jk='cat' applies it on every layer)
    hs[sub][lane] = h;
    __syncthreads();
    float jk = ADD_JK ? jkacc[(size_t)n * 64 + lane] : 0.f;
    float yn = 0.f;
#pragma unroll 8
    for (int k = 0; k < 64; ++k) {
        float hk = hs[sub][k];
        jk = fmaf(hk, jkw[k * 64 + lane], jk);
        if (HAS_NEXT) yn = fmaf(hk, wnext[k * 64 + lane], yn);
    }
    if (HAS_NEXT) {
        jkacc[(size_t)n * 64 + lane] = jk;
        ynext[(size_t)n * 64 + lane] = yn;
    } else {
        // final layer: fused global_add_pool of (jk + jk_b)
        atomicAdd(&g[batch[n] * 64 + lane], jk + jkb[lane]);
    }
}

// ---------------- final head ----------------

__global__ __launch_bounds__(64) void k_final(const float* __restrict__ g,
                                              const float* __restrict__ w1,
                                              const float* __restrict__ b1,
                                              const float* __restrict__ bng,
                                              const float* __restrict__ bnb,
                                              const float* __restrict__ bnm,
                                              const float* __restrict__ bnv,
                                              const float* __restrict__ w2,
                                              const float* __restrict__ b2,
                                              const float* __restrict__ ow,
                                              const float* __restrict__ ob,
                                              float* __restrict__ out) {
    __shared__ float gs[64];
    __shared__ float t2[64];
    __shared__ float t3[64];
    int gr = blockIdx.x, lane = threadIdx.x;
    gs[lane] = g[gr * 64 + lane];
    __syncthreads();
    float acc = b1[lane];
#pragma unroll 8
    for (int k = 0; k < 64; ++k) acc = fmaf(gs[k], w1[k * 64 + lane], acc);
    acc = (acc - bnm[lane]) * rsqrtf(bnv[lane] + 1e-5f) * bng[lane] + bnb[lane];
    t2[lane] = fmaxf(acc, 0.f);
    __syncthreads();
    float acc2 = b2[lane];
#pragma unroll 8
    for (int k = 0; k < 64; ++k) acc2 = fmaf(t2[k], w2[k * 64 + lane], acc2);
    t3[lane] = acc2;
    __syncthreads();
    if (lane < OUTD) {
        float acc3 = ob[lane];
#pragma unroll 8
        for (int k = 0; k < 64; ++k) acc3 = fmaf(t3[k], ow[k * OUTD + lane], acc3);
        out[gr * OUTD + lane] = acc3;
    }
}

extern "C" void kernel_launch(void* const* d_in, const int* in_sizes, int n_in,
                              void* d_out, int out_size, void* d_ws, size_t ws_size,
                              hipStream_t stream) {
    const float* x     = (const float*)d_in[0];
    const int*   ei    = (const int*)d_in[1];
    const int*   batch = (const int*)d_in[2];
    const float* w1_0 = (const float*)d_in[3];
    const float* b1_0 = (const float*)d_in[4];
    const float* w2_0 = (const float*)d_in[5];
    const float* b2_0 = (const float*)d_in[6];
    const float* w1_1 = (const float*)d_in[7];
    const float* b1_1 = (const float*)d_in[8];
    const float* w2_1 = (const float*)d_in[9];
    const float* b2_1 = (const float*)d_in[10];
    const float* w1_2 = (const float*)d_in[11];
    const float* b1_2 = (const float*)d_in[12];
    const float* w2_2 = (const float*)d_in[13];
    const float* b2_2 = (const float*)d_in[14];
    const float* jk_w = (const float*)d_in[15];
    const float* jk_b = (const float*)d_in[16];
    const float* ffn_w1 = (const float*)d_in[17];
    const float* ffn_b1 = (const float*)d_in[18];
    const float* bn_g = (const float*)d_in[19];
    const float* bn_b = (const float*)d_in[20];
    const float* bn_m = (const float*)d_in[21];
    const float* bn_v = (const float*)d_in[22];
    const float* ffn_w2 = (const float*)d_in[23];
    const float* ffn_b2 = (const float*)d_in[24];
    const float* out_w  = (const float*)d_in[25];
    const float* out_b  = (const float*)d_in[26];

    // workspace layout
    float* ws = (float*)d_ws;
    float* ya    = ws;                      // 3.2M floats
    float* yb    = ya + 3200000;            // 3.2M
    float* jkacc = yb + 3200000;            // 3.2M
    float* g     = jkacc + 3200000;         // 32768
    int*   deg    = (int*)(g + 32768);      // 50000
    int*   rowptr = deg + NN;               // 50001
    int*   cursor = rowptr + NN + 1;        // 50000
    int*   csr    = cursor + NN;            // 800000
    int*   bsums  = csr + NE;               // 196
    int*   boffs  = bsums + NB_SCAN;        // 196

    // ---- CSR build ----
    hipMemsetAsync(deg, 0, NN * sizeof(int), stream);
    hipMemsetAsync(g, 0, NG * 64 * sizeof(float), stream);
    k_hist<<<(NE + 255) / 256, 256, 0, stream>>>(ei, deg);
    k_scan1<<<NB_SCAN, 256, 0, stream>>>(deg, rowptr, bsums);
    k_scan2<<<1, 256, 0, stream>>>(bsums, boffs);
    k_scan3<<<NB_SCAN, 256, 0, stream>>>(rowptr, cursor, boffs);
    k_fill<<<(NE + 255) / 256, 256, 0, stream>>>(ei, cursor, csr);

    // ---- y0 = x @ w1_0 ----
    k_pre0<<<NN / 4, 256, 0, stream>>>(x, w1_0, ya);

    // ---- layer 0: ya -> (jkacc=, yb = h1 @ w1_1) ----
    k_layer<true, false><<<NN / 4, 256, 0, stream>>>(ya, rowptr, csr, b1_0, w2_0, b2_0,
                                                     w1_1, jk_w, yb, jkacc,
                                                     nullptr, nullptr, nullptr);
    // ---- layer 1: yb -> (jkacc+=, ya = h2 @ w1_2) ----
    k_layer<true, true><<<NN / 4, 256, 0, stream>>>(yb, rowptr, csr, b1_1, w2_1, b2_1,
                                                    w1_2, jk_w + 64 * 64, ya, jkacc,
                                                    nullptr, nullptr, nullptr);
    // ---- layer 2: ya -> fused jk + pool into g ----
    k_layer<false, true><<<NN / 4, 256, 0, stream>>>(ya, rowptr, csr, b1_2, w2_2, b2_2,
                                                     nullptr, jk_w + 2 * 64 * 64, nullptr, jkacc,
                                                     jk_b, batch, g);

    // ---- head ----
    k_final<<<NG, 64, 0, stream>>>(g, ffn_w1, ffn_b1, bn_g, bn_b, bn_m, bn_v,
                                   ffn_w2, ffn_b2, out_w, out_b, (float*)d_out);
}